// Round 12
// baseline (191.830 us; speedup 1.0000x reference)
//
#include <hip/hip_runtime.h>

#define N_NODES 100000
#define N_EDGES 800000
#define N_PAIRS 500000
#define SCAN_BLK 1024
#define N_SBLKS ((N_NODES + SCAN_BLK - 1) / SCAN_BLK)   // 98

#define T_TILE  1024
#define N_TILES ((N_EDGES + T_TILE - 1) / T_TILE)       // 782
#define N_BKT   256
#define NPB     391                                     // nodes per bucket
#define BCAP    4096                                    // reorder staging capacity

typedef _Float16 half4v __attribute__((ext_vector_type(4)));
typedef _Float16 half8v __attribute__((ext_vector_type(8)));
typedef float    f32x4  __attribute__((ext_vector_type(4)));

// ---------------------------------------------------------------------------
// XOR-16B LDS swizzle: byte ^= (row&7)<<4 -> fragment reads <=2-way (free).
// v_mfma_f32_16x16x16_f16: A: lane l holds A[l%16][4*(l/16)+i];
//   B: B[4*(l/16)+i][l%16]; D: D[4*(l/16)+i][l%16].
// ---------------------------------------------------------------------------
__device__ __forceinline__ int swz(int byte_off, int row) {
    return byte_off ^ ((row & 7) << 4);
}

template<int M, bool A_IS_F32>
__global__ __launch_bounds__(256) void gemm_mfma(const void* __restrict__ Ap,
                                                 const _Float16* __restrict__ Wt,
                                                 _Float16* __restrict__ C, int nRows) {
    constexpr int K  = 128;
    constexpr int CT = M / 16;
    __shared__ _Float16 Alds[64 * K];
    __shared__ _Float16 Wlds[M * K];

    const int rb = blockIdx.x * 64;

    if (A_IS_F32) {
        const float* A = (const float*)Ap;
        for (int idx = threadIdx.x; idx < 64 * (K / 4); idx += 256) {
            const int row = idx >> 5, c4 = idx & 31;
            const int rg = (rb + row < nRows) ? rb + row : nRows - 1;
            const float4 a = *(const float4*)&A[(long)rg * K + c4 * 4];
            half4v h = { (_Float16)a.x, (_Float16)a.y, (_Float16)a.z, (_Float16)a.w };
            *(half4v*)((char*)Alds + swz(row * 256 + c4 * 8, row)) = h;
        }
    } else {
        const _Float16* A = (const _Float16*)Ap;
        for (int idx = threadIdx.x; idx < 64 * (K / 8); idx += 256) {
            const int row = idx >> 4, seg = idx & 15;
            const int rg = (rb + row < nRows) ? rb + row : nRows - 1;
            const half8v h = *(const half8v*)&A[(long)rg * K + seg * 8];
            *(half8v*)((char*)Alds + swz(row * 256 + seg * 16, row)) = h;
        }
    }
    for (int idx = threadIdx.x; idx < M * (K / 8); idx += 256) {
        const int col = idx >> 4, seg = idx & 15;
        const half8v h = *(const half8v*)&Wt[col * K + seg * 8];
        *(half8v*)((char*)Wlds + swz(col * 256 + seg * 16, col)) = h;
    }
    __syncthreads();

    const int l  = threadIdx.x & 63;
    const int w  = threadIdx.x >> 6;
    const int lr = l & 15;
    const int lg = l >> 4;

    f32x4 acc[CT];
    #pragma unroll
    for (int ct = 0; ct < CT; ++ct) acc[ct] = (f32x4){0.f, 0.f, 0.f, 0.f};

    #pragma unroll
    for (int ks = 0; ks < K / 16; ++ks) {
        const int kb   = ks * 32 + lg * 8;
        const int arow = w * 16 + lr;
        const half4v af = *(const half4v*)((const char*)Alds + swz(arow * 256 + kb, arow));
        #pragma unroll
        for (int ct = 0; ct < CT; ++ct) {
            const int col = ct * 16 + lr;
            const half4v bf = *(const half4v*)((const char*)Wlds + swz(col * 256 + kb, col));
            acc[ct] = __builtin_amdgcn_mfma_f32_16x16x16f16(af, bf, acc[ct], 0, 0, 0);
        }
    }

    #pragma unroll
    for (int ct = 0; ct < CT; ++ct) {
        const int col = ct * 16 + lr;
        #pragma unroll
        for (int j = 0; j < 4; ++j) {
            const int row = rb + w * 16 + lg * 4 + j;
            if (row < nRows) C[(long)row * M + col] = (_Float16)acc[ct][j];
        }
    }
}

// ---------------------------------------------------------------------------
// FUSED: g2[64 rows, 64] = relu(A_sp @ g1)[tile] @ Wt2^T.  512 thr / 8 waves.
// ---------------------------------------------------------------------------
__global__ __launch_bounds__(512) void spmm_gemm_fused(const int* __restrict__ rowptr,
                                                       const long long* __restrict__ epack,
                                                       const _Float16* __restrict__ g,
                                                       const _Float16* __restrict__ Wt2,
                                                       _Float16* __restrict__ g2, int nRows) {
    constexpr int K = 128, M = 64;
    __shared__ _Float16 Alds[64 * K];
    __shared__ _Float16 Wlds[M * K];

    const int rb = blockIdx.x * 64;

    for (int idx = threadIdx.x; idx < M * (K / 8); idx += 512) {
        const int col = idx >> 4, seg = idx & 15;
        const half8v h = *(const half8v*)&Wt2[col * K + seg * 8];
        *(half8v*)((char*)Wlds + swz(col * 256 + seg * 16, col)) = h;
    }

    const int li = threadIdx.x & 15;
    const int rs = threadIdx.x >> 4;        // 0..31
    #pragma unroll
    for (int s = 0; s < 2; ++s) {
        const int lrow = s * 32 + rs;
        const int r  = rb + lrow;
        const int rc = (r < nRows) ? r : nRows - 1;
        const int lo = rowptr[rc], hi = rowptr[rc + 1];
        float acc[8] = {0.f, 0.f, 0.f, 0.f, 0.f, 0.f, 0.f, 0.f};
        #pragma unroll 4
        for (int e = lo; e < hi; ++e) {
            const long long pk = epack[e];
            const int   c = (int)pk;
            const float v = __int_as_float((int)(pk >> 32));
            const half8v m = *(const half8v*)&g[(long)c * K + li * 8];
            #pragma unroll
            for (int j = 0; j < 8; ++j) acc[j] += v * (float)m[j];
        }
        half8v h;
        #pragma unroll
        for (int j = 0; j < 8; ++j) h[j] = (_Float16)fmaxf(acc[j], 0.f);
        *(half8v*)((char*)Alds + swz(lrow * 256 + li * 16, lrow)) = h;
    }
    __syncthreads();

    const int l    = threadIdx.x & 63;
    const int w    = threadIdx.x >> 6;      // 0..7
    const int lr   = l & 15;
    const int lg   = l >> 4;
    const int rowg = w >> 1;                // 0..3
    const int colb = (w & 1) * 32;          // 0 or 32

    f32x4 acc[2];
    acc[0] = (f32x4){0.f, 0.f, 0.f, 0.f};
    acc[1] = (f32x4){0.f, 0.f, 0.f, 0.f};

    #pragma unroll
    for (int ks = 0; ks < K / 16; ++ks) {
        const int kb   = ks * 32 + lg * 8;
        const int arow = rowg * 16 + lr;
        const half4v af = *(const half4v*)((const char*)Alds + swz(arow * 256 + kb, arow));
        #pragma unroll
        for (int ct = 0; ct < 2; ++ct) {
            const int col = colb + ct * 16 + lr;
            const half4v bf = *(const half4v*)((const char*)Wlds + swz(col * 256 + kb, col));
            acc[ct] = __builtin_amdgcn_mfma_f32_16x16x16f16(af, bf, acc[ct], 0, 0, 0);
        }
    }

    #pragma unroll
    for (int ct = 0; ct < 2; ++ct) {
        const int col = colb + ct * 16 + lr;
        #pragma unroll
        for (int j = 0; j < 4; ++j) {
            const int row = rb + rowg * 16 + lg * 4 + j;
            if (row < nRows) g2[(long)row * M + col] = (_Float16)acc[ct][j];
        }
    }
}

// ---------------------------------------------------------------------------
// hist_both (+ fused weight transpose in the extra block):
// blocks 0..N_TILES-1: per-node deg atomics + per-(tile,bucket) histogram
//   (hist layout [tile][bucket] -> fully coalesced 256-int write per block).
// block N_TILES: Wt[m][k] = (half)W[k][m].
// T_TILE=1024 -> 783 blocks (~12 waves/CU): R11's 197-block version sat at
// 4.8% occupancy, 55 us, latency-bound.
// ---------------------------------------------------------------------------
__global__ __launch_bounds__(256) void hist_both(const int* __restrict__ erows,
                                                 int* __restrict__ deg,
                                                 int* __restrict__ hist,
                                                 const float* __restrict__ W1,
                                                 const float* __restrict__ W2,
                                                 _Float16* __restrict__ Wt1,
                                                 _Float16* __restrict__ Wt2) {
    if (blockIdx.x == N_TILES) {
        for (int i = threadIdx.x; i < 128 * 128; i += 256) {
            const int k = i >> 7, m = i & 127;
            Wt1[m * 128 + k] = (_Float16)W1[i];
        }
        for (int i = threadIdx.x; i < 128 * 64; i += 256) {
            const int k = i >> 6, m = i & 63;
            Wt2[m * 128 + k] = (_Float16)W2[i];
        }
        return;
    }
    __shared__ int cnt[N_BKT];
    cnt[threadIdx.x] = 0;
    __syncthreads();
    const int e0 = blockIdx.x * T_TILE;
    const int e1 = min(e0 + T_TILE, N_EDGES);
    for (int e = e0 + threadIdx.x; e < e1; e += 256) {
        const int r = erows[e];
        atomicAdd(&deg[r], 1);
        atomicAdd(&cnt[r / NPB], 1);
    }
    __syncthreads();
    hist[blockIdx.x * N_BKT + threadIdx.x] = cnt[threadIdx.x];
}

// ---------------------------------------------------------------------------
// scan_phase12: per-block reduce of deg -> bsum; LAST block also scans the
// 98 block sums (inline phase2) -> boff + rowptr[N].  done zeroed by memset.
// ---------------------------------------------------------------------------
__global__ __launch_bounds__(SCAN_BLK) void scan_phase12(const int* __restrict__ deg,
                                                         int* __restrict__ bsum,
                                                         int* __restrict__ boff,
                                                         int* __restrict__ rowptr,
                                                         int* __restrict__ done) {
    const int i = blockIdx.x * SCAN_BLK + threadIdx.x;
    int v = (i < N_NODES) ? deg[i] : 0;
    #pragma unroll
    for (int off = 1; off < 64; off <<= 1) v += __shfl_xor(v, off);
    __shared__ int ws[SCAN_BLK / 64];
    if ((threadIdx.x & 63) == 0) ws[threadIdx.x >> 6] = v;
    __syncthreads();
    if (threadIdx.x < SCAN_BLK / 64) {
        int s = ws[threadIdx.x];
        #pragma unroll
        for (int off = 1; off < SCAN_BLK / 64; off <<= 1) s += __shfl_xor(s, off);
        if (threadIdx.x == 0) bsum[blockIdx.x] = s;
    }
    __shared__ int lastf;
    if (threadIdx.x == 0) {
        __threadfence();
        lastf = (atomicAdd(done, 1) == gridDim.x - 1) ? 1 : 0;
    }
    __syncthreads();
    if (lastf) {
        __threadfence();
        __shared__ int lds2[128];
        const int t = threadIdx.x;
        int val = 0;
        if (t < 128) {
            val = (t < N_SBLKS) ? bsum[t] : 0;
            lds2[t] = val;
        }
        __syncthreads();
        for (int off = 1; off < 128; off <<= 1) {
            int u = (t < 128 && t >= off) ? lds2[t - off] : 0;
            __syncthreads();
            if (t < 128) lds2[t] += u;
            __syncthreads();
        }
        if (t < N_SBLKS) boff[t] = lds2[t] - val;
        if (t == N_SBLKS - 1) rowptr[N_NODES] = lds2[t];
    }
}

__global__ __launch_bounds__(SCAN_BLK) void scan_phase3(const int* __restrict__ deg,
                                                        const int* __restrict__ boff,
                                                        int* __restrict__ rowptr) {
    const int i    = blockIdx.x * SCAN_BLK + threadIdx.x;
    const int lane = threadIdx.x & 63;
    const int wid  = threadIdx.x >> 6;
    const int v = (i < N_NODES) ? deg[i] : 0;
    int s = v;
    #pragma unroll
    for (int off = 1; off < 64; off <<= 1) {
        int u = __shfl_up(s, off);
        if (lane >= off) s += u;
    }
    __shared__ int wsum[SCAN_BLK / 64];
    __shared__ int woff[SCAN_BLK / 64];
    if (lane == 63) wsum[wid] = s;
    __syncthreads();
    if (threadIdx.x < SCAN_BLK / 64) {
        const int t0 = wsum[threadIdx.x];
        int q = t0;
        #pragma unroll
        for (int off = 1; off < SCAN_BLK / 64; off <<= 1) {
            int u = __shfl_up(q, off);
            if ((int)threadIdx.x >= off) q += u;
        }
        woff[threadIdx.x] = q - t0;
    }
    __syncthreads();
    const int ex = (s - v) + woff[wid] + boff[blockIdx.x];
    if (i < N_NODES) rowptr[i] = ex;
}

// ---------------------------------------------------------------------------
// Edge partition into CSR order (2-level).
// hist layout [tile][bucket]; off layout [bucket][tile] (coalesced writes).
// tmp record: [val:32][lrow:9][col:17].  Final: [val:32][col:32].
// ---------------------------------------------------------------------------
__global__ __launch_bounds__(1024) void bucket_scan(const int* __restrict__ hist,
                                                    const int* __restrict__ rowptr,
                                                    int* __restrict__ off) {
    __shared__ int lds[1024];
    const int b = blockIdx.x;
    const int t = threadIdx.x;
    const int v = (t < N_TILES) ? hist[t * N_BKT + b] : 0;
    lds[t] = v;
    __syncthreads();
    for (int o = 1; o < 1024; o <<= 1) {
        int u = (t >= o) ? lds[t - o] : 0;
        __syncthreads();
        lds[t] += u;
        __syncthreads();
    }
    if (t < N_TILES) off[b * N_TILES + t] = rowptr[b * NPB] + lds[t] - v;
}

__global__ __launch_bounds__(256) void partition(const int* __restrict__ erows,
                                                 const int* __restrict__ ecols,
                                                 const float* __restrict__ evals,
                                                 const int* __restrict__ off,
                                                 unsigned long long* __restrict__ etmp) {
    __shared__ int cur[N_BKT];
    cur[threadIdx.x] = off[threadIdx.x * N_TILES + blockIdx.x];
    __syncthreads();
    const int e0 = blockIdx.x * T_TILE;
    const int e1 = min(e0 + T_TILE, N_EDGES);
    for (int e = e0 + threadIdx.x; e < e1; e += 256) {
        const int r = erows[e];
        const int b = r / NPB;
        const int lrow = r - b * NPB;
        const int p = atomicAdd(&cur[b], 1);
        etmp[p] = ((unsigned long long)(unsigned)__float_as_int(evals[e]) << 32)
                | ((unsigned)lrow << 17) | (unsigned)ecols[e];
    }
}

__global__ __launch_bounds__(256) void bucket_reorder(const int* __restrict__ rowptr,
                                                      const unsigned long long* __restrict__ etmp,
                                                      unsigned long long* __restrict__ epack) {
    __shared__ int lcur[NPB];
    __shared__ unsigned long long stg[BCAP];
    const int b    = blockIdx.x;
    const int lo   = b * NPB;
    const int hiN  = min(lo + NPB, N_NODES);
    const int base = rowptr[lo];
    const int cnt  = rowptr[hiN] - base;
    for (int j = threadIdx.x; j < hiN - lo; j += 256)
        lcur[j] = rowptr[lo + j] - base;
    __syncthreads();
    for (int i = threadIdx.x; i < cnt; i += 256) {
        const unsigned long long p = etmp[base + i];
        const int lrow = (int)((p >> 17) & 0x1FF);
        const int pos  = atomicAdd(&lcur[lrow], 1);
        const unsigned long long rec = (p & 0xFFFFFFFF00000000ULL) | (p & 0x1FFFFULL);
        if (pos < BCAP) stg[pos] = rec;
        else epack[base + pos] = rec;   // safety fallback (statistically never)
    }
    __syncthreads();
    const int n = min(cnt, BCAP);
    for (int i = threadIdx.x; i < n; i += 256)
        epack[base + i] = stg[i];
}

// ---------------------------------------------------------------------------
// CSR SpMM (gather, fp16 data, f32 accumulate): agg[r] = sum vals*g[cols]
// ---------------------------------------------------------------------------
template<int D, bool RELU>
__global__ __launch_bounds__(256) void spmm_csr_h(const int* __restrict__ rowptr,
                                                  const long long* __restrict__ epack,
                                                  const _Float16* __restrict__ g,
                                                  _Float16* __restrict__ agg, int nRows) {
    constexpr int LPR = D / 8;
    constexpr int RPB = 256 / LPR;
    const int r  = blockIdx.x * RPB + threadIdx.x / LPR;
    const int li = threadIdx.x % LPR;
    if (r >= nRows) return;
    const int lo = rowptr[r], hi = rowptr[r + 1];
    float acc[8] = {0.f, 0.f, 0.f, 0.f, 0.f, 0.f, 0.f, 0.f};
    #pragma unroll 4
    for (int e = lo; e < hi; ++e) {
        const long long pk = epack[e];
        const int   c = (int)pk;
        const float v = __int_as_float((int)(pk >> 32));
        const half8v m = *(const half8v*)&g[(long)c * D + li * 8];
        #pragma unroll
        for (int j = 0; j < 8; ++j) acc[j] += v * (float)m[j];
    }
    half8v o;
    #pragma unroll
    for (int j = 0; j < 8; ++j) {
        float a = RELU ? fmaxf(acc[j], 0.f) : acc[j];
        o[j] = (_Float16)a;
    }
    *(half8v*)&agg[(long)r * D + li * 8] = o;
}

// ---------------------------------------------------------------------------
// Decode: 2 pairs per thread (independent gather chains), 8 lanes per pair.
// ---------------------------------------------------------------------------
__global__ __launch_bounds__(256) void decode_dot(const _Float16* __restrict__ h2,
                                                  const int2* __restrict__ pairs,
                                                  float* __restrict__ out, int nPairs) {
    const int tid  = blockIdx.x * 256 + threadIdx.x;
    const int half = (nPairs + 1) / 2;
    const int p0   = tid >> 3;
    const int lane = tid & 7;
    if (p0 >= half) return;
    const int p1 = p0 + half;
    const bool has1 = p1 < nPairs;
    const int2 pr0 = pairs[p0];
    const int2 pr1 = has1 ? pairs[p1] : pr0;
    const half8v a0 = *(const half8v*)&h2[(long)pr0.x * 64 + lane * 8];
    const half8v b0 = *(const half8v*)&h2[(long)pr0.y * 64 + lane * 8];
    const half8v a1 = *(const half8v*)&h2[(long)pr1.x * 64 + lane * 8];
    const half8v b1 = *(const half8v*)&h2[(long)pr1.y * 64 + lane * 8];
    float s0 = 0.f, s1 = 0.f;
    #pragma unroll
    for (int j = 0; j < 8; ++j) {
        s0 += (float)a0[j] * (float)b0[j];
        s1 += (float)a1[j] * (float)b1[j];
    }
    s0 += __shfl_xor(s0, 1); s1 += __shfl_xor(s1, 1);
    s0 += __shfl_xor(s0, 2); s1 += __shfl_xor(s1, 2);
    s0 += __shfl_xor(s0, 4); s1 += __shfl_xor(s1, 4);
    if (lane == 0) {
        out[p0] = s0;
        if (has1) out[p1] = s1;
    }
}

// ---------------------------------------------------------------------------
extern "C" void kernel_launch(void* const* d_in, const int* in_sizes, int n_in,
                              void* d_out, int out_size, void* d_ws, size_t ws_size,
                              hipStream_t stream) {
    const float* x     = (const float*)d_in[0];
    const int*   erows = (const int*)d_in[1];
    const int*   ecols = (const int*)d_in[2];
    const float* evals = (const float*)d_in[3];
    const int2*  pairs = (const int2*)d_in[4];
    const float* W1    = (const float*)d_in[5];
    const float* W2    = (const float*)d_in[6];
    float* out = (float*)d_out;

    char* ws = (char*)d_ws;
    _Float16*           g1     = (_Float16*)          (ws);              //  0      .. 25.6M
    _Float16*           g2     = (_Float16*)          (ws + 25600000);   // 25.6M  .. 38.4M
    _Float16*           agg2   = (_Float16*)          (ws + 38400000);   // 38.4M  .. 51.2M
    int*                rowptr = (int*)               (ws + 51200000);   // +400,016
    int*                deg    = (int*)               (ws + 51600016);   // +400,000
    int*                done   = (int*)               (ws + 52000016);   // +16
    unsigned long long* epack  = (unsigned long long*)(ws + 52000032);   // +6,400,000
    int*                bsum   = (int*)               (ws + 58400032);   // +512
    int*                boff   = (int*)               (ws + 58400544);   // +512
    _Float16*           Wt1    = (_Float16*)          (ws + 58401056);   // +32,768
    _Float16*           Wt2    = (_Float16*)          (ws + 58433824);   // +16,384
    int*                hist   = (int*)               (ws + 58450208);   // +800,768
    int*                off    = (int*)               (ws + 59250976);   // +800,768
    unsigned long long* etmp   = (unsigned long long*)(ws + 60051744);   // +6,400,000 -> 66.5M

    // --- deg + done zero; fused hist + weight transpose ---
    hipMemsetAsync(deg, 0, (size_t)N_NODES * 4 + 16, stream);
    hist_both<<<N_TILES + 1, 256, 0, stream>>>(erows, deg, hist, W1, W2, Wt1, Wt2);
    scan_phase12<<<N_SBLKS, SCAN_BLK, 0, stream>>>(deg, bsum, boff, rowptr, done);
    scan_phase3<<<N_SBLKS, SCAN_BLK, 0, stream>>>(deg, boff, rowptr);

    // --- edge partition into CSR order ---
    bucket_scan<<<N_BKT, 1024, 0, stream>>>(hist, rowptr, off);
    partition<<<N_TILES, 256, 0, stream>>>(erows, ecols, evals, off, etmp);
    bucket_reorder<<<N_BKT, 256, 0, stream>>>(rowptr, etmp, epack);

    // --- Layer 1 GEMM: g1 = x @ W1 (f16) ---
    gemm_mfma<128, true><<<(N_NODES + 63) / 64, 256, 0, stream>>>(x, Wt1, g1, N_NODES);

    // --- FUSED Layer1-aggregate + Layer2 GEMM: g2 = relu(A_sp@g1) @ W2 ---
    spmm_gemm_fused<<<(N_NODES + 63) / 64, 512, 0, stream>>>(
        rowptr, (const long long*)epack, g1, Wt2, g2, N_NODES);

    // --- Layer 2 aggregate: agg2 = A_sp @ g2 ---
    spmm_csr_h<64, false><<<(N_NODES + 31) / 32, 256, 0, stream>>>(
        rowptr, (const long long*)epack, g2, agg2, N_NODES);

    // --- Decode ---
    decode_dot<<<((N_PAIRS + 1) / 2 * 8 + 255) / 256, 256, 0, stream>>>(
        agg2, pairs, out, N_PAIRS);
}

// Round 13
// 146.008 us; speedup vs baseline: 1.3138x; 1.3138x over previous
//
#include <hip/hip_runtime.h>

#define N_NODES 100000
#define N_EDGES 800000
#define N_PAIRS 500000

#define T_TILE  2048
#define N_TILES ((N_EDGES + T_TILE - 1) / T_TILE)       // 391
#define N_BKT   256
#define NPB     391                                     // nodes per bucket (256*391 >= 100000)
#define BCAP    4096                                    // reorder staging capacity

typedef _Float16 half4v __attribute__((ext_vector_type(4)));
typedef _Float16 half8v __attribute__((ext_vector_type(8)));
typedef float    f32x4  __attribute__((ext_vector_type(4)));

// ---------------------------------------------------------------------------
// XOR-16B LDS swizzle: byte ^= (row&7)<<4 -> fragment reads <=2-way (free).
// v_mfma_f32_16x16x16_f16: A: lane l holds A[l%16][4*(l/16)+i];
//   B: B[4*(l/16)+i][l%16]; D: D[4*(l/16)+i][l%16].
// ---------------------------------------------------------------------------
__device__ __forceinline__ int swz(int byte_off, int row) {
    return byte_off ^ ((row & 7) << 4);
}

template<int M, bool A_IS_F32>
__global__ __launch_bounds__(256) void gemm_mfma(const void* __restrict__ Ap,
                                                 const _Float16* __restrict__ Wt,
                                                 _Float16* __restrict__ C, int nRows) {
    constexpr int K  = 128;
    constexpr int CT = M / 16;
    __shared__ _Float16 Alds[64 * K];
    __shared__ _Float16 Wlds[M * K];

    const int rb = blockIdx.x * 64;

    if (A_IS_F32) {
        const float* A = (const float*)Ap;
        for (int idx = threadIdx.x; idx < 64 * (K / 4); idx += 256) {
            const int row = idx >> 5, c4 = idx & 31;
            const int rg = (rb + row < nRows) ? rb + row : nRows - 1;
            const float4 a = *(const float4*)&A[(long)rg * K + c4 * 4];
            half4v h = { (_Float16)a.x, (_Float16)a.y, (_Float16)a.z, (_Float16)a.w };
            *(half4v*)((char*)Alds + swz(row * 256 + c4 * 8, row)) = h;
        }
    } else {
        const _Float16* A = (const _Float16*)Ap;
        for (int idx = threadIdx.x; idx < 64 * (K / 8); idx += 256) {
            const int row = idx >> 4, seg = idx & 15;
            const int rg = (rb + row < nRows) ? rb + row : nRows - 1;
            const half8v h = *(const half8v*)&A[(long)rg * K + seg * 8];
            *(half8v*)((char*)Alds + swz(row * 256 + seg * 16, row)) = h;
        }
    }
    for (int idx = threadIdx.x; idx < M * (K / 8); idx += 256) {
        const int col = idx >> 4, seg = idx & 15;
        const half8v h = *(const half8v*)&Wt[col * K + seg * 8];
        *(half8v*)((char*)Wlds + swz(col * 256 + seg * 16, col)) = h;
    }
    __syncthreads();

    const int l  = threadIdx.x & 63;
    const int w  = threadIdx.x >> 6;
    const int lr = l & 15;
    const int lg = l >> 4;

    f32x4 acc[CT];
    #pragma unroll
    for (int ct = 0; ct < CT; ++ct) acc[ct] = (f32x4){0.f, 0.f, 0.f, 0.f};

    #pragma unroll
    for (int ks = 0; ks < K / 16; ++ks) {
        const int kb   = ks * 32 + lg * 8;
        const int arow = w * 16 + lr;
        const half4v af = *(const half4v*)((const char*)Alds + swz(arow * 256 + kb, arow));
        #pragma unroll
        for (int ct = 0; ct < CT; ++ct) {
            const int col = ct * 16 + lr;
            const half4v bf = *(const half4v*)((const char*)Wlds + swz(col * 256 + kb, col));
            acc[ct] = __builtin_amdgcn_mfma_f32_16x16x16f16(af, bf, acc[ct], 0, 0, 0);
        }
    }

    #pragma unroll
    for (int ct = 0; ct < CT; ++ct) {
        const int col = ct * 16 + lr;
        #pragma unroll
        for (int j = 0; j < 4; ++j) {
            const int row = rb + w * 16 + lg * 4 + j;
            if (row < nRows) C[(long)row * M + col] = (_Float16)acc[ct][j];
        }
    }
}

// ---------------------------------------------------------------------------
// FUSED: g2[64 rows, 64] = relu(A_sp @ g1)[tile] @ Wt2^T.  512 thr / 8 waves.
// ---------------------------------------------------------------------------
__global__ __launch_bounds__(512) void spmm_gemm_fused(const int* __restrict__ rowptr,
                                                       const long long* __restrict__ epack,
                                                       const _Float16* __restrict__ g,
                                                       const _Float16* __restrict__ Wt2,
                                                       _Float16* __restrict__ g2, int nRows) {
    constexpr int K = 128, M = 64;
    __shared__ _Float16 Alds[64 * K];
    __shared__ _Float16 Wlds[M * K];

    const int rb = blockIdx.x * 64;

    for (int idx = threadIdx.x; idx < M * (K / 8); idx += 512) {
        const int col = idx >> 4, seg = idx & 15;
        const half8v h = *(const half8v*)&Wt2[col * K + seg * 8];
        *(half8v*)((char*)Wlds + swz(col * 256 + seg * 16, col)) = h;
    }

    const int li = threadIdx.x & 15;
    const int rs = threadIdx.x >> 4;        // 0..31
    #pragma unroll
    for (int s = 0; s < 2; ++s) {
        const int lrow = s * 32 + rs;
        const int r  = rb + lrow;
        const int rc = (r < nRows) ? r : nRows - 1;
        const int lo = rowptr[rc], hi = rowptr[rc + 1];
        float acc[8] = {0.f, 0.f, 0.f, 0.f, 0.f, 0.f, 0.f, 0.f};
        #pragma unroll 4
        for (int e = lo; e < hi; ++e) {
            const long long pk = epack[e];
            const int   c = (int)pk;
            const float v = __int_as_float((int)(pk >> 32));
            const half8v m = *(const half8v*)&g[(long)c * K + li * 8];
            #pragma unroll
            for (int j = 0; j < 8; ++j) acc[j] += v * (float)m[j];
        }
        half8v h;
        #pragma unroll
        for (int j = 0; j < 8; ++j) h[j] = (_Float16)fmaxf(acc[j], 0.f);
        *(half8v*)((char*)Alds + swz(lrow * 256 + li * 16, lrow)) = h;
    }
    __syncthreads();

    const int l    = threadIdx.x & 63;
    const int w    = threadIdx.x >> 6;      // 0..7
    const int lr   = l & 15;
    const int lg   = l >> 4;
    const int rowg = w >> 1;                // 0..3
    const int colb = (w & 1) * 32;          // 0 or 32

    f32x4 acc[2];
    acc[0] = (f32x4){0.f, 0.f, 0.f, 0.f};
    acc[1] = (f32x4){0.f, 0.f, 0.f, 0.f};

    #pragma unroll
    for (int ks = 0; ks < K / 16; ++ks) {
        const int kb   = ks * 32 + lg * 8;
        const int arow = rowg * 16 + lr;
        const half4v af = *(const half4v*)((const char*)Alds + swz(arow * 256 + kb, arow));
        #pragma unroll
        for (int ct = 0; ct < 2; ++ct) {
            const int col = colb + ct * 16 + lr;
            const half4v bf = *(const half4v*)((const char*)Wlds + swz(col * 256 + kb, col));
            acc[ct] = __builtin_amdgcn_mfma_f32_16x16x16f16(af, bf, acc[ct], 0, 0, 0);
        }
    }

    #pragma unroll
    for (int ct = 0; ct < 2; ++ct) {
        const int col = colb + ct * 16 + lr;
        #pragma unroll
        for (int j = 0; j < 4; ++j) {
            const int row = rb + rowg * 16 + lg * 4 + j;
            if (row < nRows) g2[(long)row * M + col] = (_Float16)acc[ct][j];
        }
    }
}

// ---------------------------------------------------------------------------
// hist_both: per-(tile,bucket) LDS histogram ONLY — no per-node global
// atomics (R12: 800K deg atomicAdds = 25.8 MB WRITE, 55 us; per-node degrees
// are now derived locally in bucket_reorder).  Block N_TILES: W transpose.
// ---------------------------------------------------------------------------
__global__ __launch_bounds__(256) void hist_both(const int* __restrict__ erows,
                                                 int* __restrict__ hist,
                                                 const float* __restrict__ W1,
                                                 const float* __restrict__ W2,
                                                 _Float16* __restrict__ Wt1,
                                                 _Float16* __restrict__ Wt2) {
    if (blockIdx.x == N_TILES) {
        for (int i = threadIdx.x; i < 128 * 128; i += 256) {
            const int k = i >> 7, m = i & 127;
            Wt1[m * 128 + k] = (_Float16)W1[i];
        }
        for (int i = threadIdx.x; i < 128 * 64; i += 256) {
            const int k = i >> 6, m = i & 63;
            Wt2[m * 128 + k] = (_Float16)W2[i];
        }
        return;
    }
    __shared__ int cnt[N_BKT];
    cnt[threadIdx.x] = 0;
    __syncthreads();
    const int e0 = blockIdx.x * T_TILE;
    const int e1 = min(e0 + T_TILE, N_EDGES);
    for (int e = e0 + threadIdx.x; e < e1; e += 256)
        atomicAdd(&cnt[erows[e] / NPB], 1);
    __syncthreads();
    hist[blockIdx.x * N_BKT + threadIdx.x] = cnt[threadIdx.x];
}

// ---------------------------------------------------------------------------
// bucket_scan: per-bucket prefix over its tile counts -> offpart[b][t], plus
// bucket total bt[b].  hist layout [tile][bucket].
// ---------------------------------------------------------------------------
__global__ __launch_bounds__(512) void bucket_scan(const int* __restrict__ hist,
                                                   int* __restrict__ offpart,
                                                   int* __restrict__ bt) {
    __shared__ int lds[512];
    const int b = blockIdx.x;
    const int t = threadIdx.x;
    const int v = (t < N_TILES) ? hist[t * N_BKT + b] : 0;
    lds[t] = v;
    __syncthreads();
    for (int o = 1; o < 512; o <<= 1) {
        int u = (t >= o) ? lds[t - o] : 0;
        __syncthreads();
        lds[t] += u;
        __syncthreads();
    }
    if (t < N_TILES) offpart[b * N_TILES + t] = lds[t] - v;
    if (t == 511) bt[b] = lds[511];
}

// bkt_base: exclusive scan of 256 bucket totals -> bbase[0..256].
__global__ __launch_bounds__(256) void bkt_base(const int* __restrict__ bt,
                                                int* __restrict__ bbase) {
    __shared__ int lds[256];
    const int t = threadIdx.x;
    const int v = bt[t];
    lds[t] = v;
    __syncthreads();
    for (int o = 1; o < 256; o <<= 1) {
        int u = (t >= o) ? lds[t - o] : 0;
        __syncthreads();
        lds[t] += u;
        __syncthreads();
    }
    bbase[t] = lds[t] - v;
    if (t == 255) bbase[256] = lds[255];
}

// ---------------------------------------------------------------------------
// partition: coarse scatter into per-bucket regions (tmp order).
// tmp record: [val:32][lrow:9][col:17].
// ---------------------------------------------------------------------------
__global__ __launch_bounds__(256) void partition(const int* __restrict__ erows,
                                                 const int* __restrict__ ecols,
                                                 const float* __restrict__ evals,
                                                 const int* __restrict__ offpart,
                                                 const int* __restrict__ bbase,
                                                 unsigned long long* __restrict__ etmp) {
    __shared__ int cur[N_BKT];
    cur[threadIdx.x] = bbase[threadIdx.x] + offpart[threadIdx.x * N_TILES + blockIdx.x];
    __syncthreads();
    const int e0 = blockIdx.x * T_TILE;
    const int e1 = min(e0 + T_TILE, N_EDGES);
    for (int e = e0 + threadIdx.x; e < e1; e += 256) {
        const int r = erows[e];
        const int b = r / NPB;
        const int lrow = r - b * NPB;
        const int p = atomicAdd(&cur[b], 1);
        etmp[p] = ((unsigned long long)(unsigned)__float_as_int(evals[e]) << 32)
                | ((unsigned)lrow << 17) | (unsigned)ecols[e];
    }
}

// ---------------------------------------------------------------------------
// bucket_reorder: per-bucket — count local degrees (LDS), local scan,
// WRITE rowptr, then rank records into final CSR order (LDS staging).
// Final record: [val:32][col:32].
// ---------------------------------------------------------------------------
__global__ __launch_bounds__(256) void bucket_reorder(const int* __restrict__ bbase,
                                                      const unsigned long long* __restrict__ etmp,
                                                      unsigned long long* __restrict__ epack,
                                                      int* __restrict__ rowptr) {
    __shared__ int lcnt[NPB + 1];
    __shared__ int psum[256];
    __shared__ int lcur[NPB];
    __shared__ unsigned long long stg[BCAP];
    const int b    = blockIdx.x;
    const int t    = threadIdx.x;
    const int lo   = b * NPB;
    const int hiN  = min(lo + NPB, N_NODES);
    const int nloc = hiN - lo;
    const int base = bbase[b];
    const int cnt  = bbase[b + 1] - base;

    for (int j = t; j < NPB; j += 256) lcnt[j] = 0;
    __syncthreads();
    // pass A: count local degrees
    for (int i = t; i < cnt; i += 256)
        atomicAdd(&lcnt[(int)((etmp[base + i] >> 17) & 0x1FF)], 1);
    __syncthreads();
    // local exclusive scan over NPB=391 counters (2 slots per thread)
    const int j0 = 2 * t, j1 = 2 * t + 1;
    const int a0 = (j0 < NPB) ? lcnt[j0] : 0;
    const int a1 = (j1 < NPB) ? lcnt[j1] : 0;
    psum[t] = a0 + a1;
    __syncthreads();
    for (int o = 1; o < 256; o <<= 1) {
        int u = (t >= o) ? psum[t - o] : 0;
        __syncthreads();
        psum[t] += u;
        __syncthreads();
    }
    const int ex0 = psum[t] - (a0 + a1);
    const int ex1 = ex0 + a0;
    if (j0 < NPB) lcur[j0] = ex0;
    if (j1 < NPB) lcur[j1] = ex1;
    if (j0 < nloc) rowptr[lo + j0] = base + ex0;
    if (j1 < nloc) rowptr[lo + j1] = base + ex1;
    if (b == N_BKT - 1 && t == 0) rowptr[N_NODES] = N_EDGES;
    __syncthreads();
    // pass B: rank + stage + linear writeback
    for (int i = t; i < cnt; i += 256) {
        const unsigned long long p = etmp[base + i];
        const int lrow = (int)((p >> 17) & 0x1FF);
        const int pos  = atomicAdd(&lcur[lrow], 1);
        const unsigned long long rec = (p & 0xFFFFFFFF00000000ULL) | (p & 0x1FFFFULL);
        if (pos < BCAP) stg[pos] = rec;
        else epack[base + pos] = rec;   // safety fallback (statistically never)
    }
    __syncthreads();
    const int n = min(cnt, BCAP);
    for (int i = t; i < n; i += 256)
        epack[base + i] = stg[i];
}

// ---------------------------------------------------------------------------
// CSR SpMM (gather, fp16 data, f32 accumulate): agg[r] = sum vals*g[cols]
// ---------------------------------------------------------------------------
template<int D, bool RELU>
__global__ __launch_bounds__(256) void spmm_csr_h(const int* __restrict__ rowptr,
                                                  const long long* __restrict__ epack,
                                                  const _Float16* __restrict__ g,
                                                  _Float16* __restrict__ agg, int nRows) {
    constexpr int LPR = D / 8;
    constexpr int RPB = 256 / LPR;
    const int r  = blockIdx.x * RPB + threadIdx.x / LPR;
    const int li = threadIdx.x % LPR;
    if (r >= nRows) return;
    const int lo = rowptr[r], hi = rowptr[r + 1];
    float acc[8] = {0.f, 0.f, 0.f, 0.f, 0.f, 0.f, 0.f, 0.f};
    #pragma unroll 4
    for (int e = lo; e < hi; ++e) {
        const long long pk = epack[e];
        const int   c = (int)pk;
        const float v = __int_as_float((int)(pk >> 32));
        const half8v m = *(const half8v*)&g[(long)c * D + li * 8];
        #pragma unroll
        for (int j = 0; j < 8; ++j) acc[j] += v * (float)m[j];
    }
    half8v o;
    #pragma unroll
    for (int j = 0; j < 8; ++j) {
        float a = RELU ? fmaxf(acc[j], 0.f) : acc[j];
        o[j] = (_Float16)a;
    }
    *(half8v*)&agg[(long)r * D + li * 8] = o;
}

// ---------------------------------------------------------------------------
// Decode: 2 pairs per thread (independent gather chains), 8 lanes per pair.
// ---------------------------------------------------------------------------
__global__ __launch_bounds__(256) void decode_dot(const _Float16* __restrict__ h2,
                                                  const int2* __restrict__ pairs,
                                                  float* __restrict__ out, int nPairs) {
    const int tid  = blockIdx.x * 256 + threadIdx.x;
    const int half = (nPairs + 1) / 2;
    const int p0   = tid >> 3;
    const int lane = tid & 7;
    if (p0 >= half) return;
    const int p1 = p0 + half;
    const bool has1 = p1 < nPairs;
    const int2 pr0 = pairs[p0];
    const int2 pr1 = has1 ? pairs[p1] : pr0;
    const half8v a0 = *(const half8v*)&h2[(long)pr0.x * 64 + lane * 8];
    const half8v b0 = *(const half8v*)&h2[(long)pr0.y * 64 + lane * 8];
    const half8v a1 = *(const half8v*)&h2[(long)pr1.x * 64 + lane * 8];
    const half8v b1 = *(const half8v*)&h2[(long)pr1.y * 64 + lane * 8];
    float s0 = 0.f, s1 = 0.f;
    #pragma unroll
    for (int j = 0; j < 8; ++j) {
        s0 += (float)a0[j] * (float)b0[j];
        s1 += (float)a1[j] * (float)b1[j];
    }
    s0 += __shfl_xor(s0, 1); s1 += __shfl_xor(s1, 1);
    s0 += __shfl_xor(s0, 2); s1 += __shfl_xor(s1, 2);
    s0 += __shfl_xor(s0, 4); s1 += __shfl_xor(s1, 4);
    if (lane == 0) {
        out[p0] = s0;
        if (has1) out[p1] = s1;
    }
}

// ---------------------------------------------------------------------------
extern "C" void kernel_launch(void* const* d_in, const int* in_sizes, int n_in,
                              void* d_out, int out_size, void* d_ws, size_t ws_size,
                              hipStream_t stream) {
    const float* x     = (const float*)d_in[0];
    const int*   erows = (const int*)d_in[1];
    const int*   ecols = (const int*)d_in[2];
    const float* evals = (const float*)d_in[3];
    const int2*  pairs = (const int2*)d_in[4];
    const float* W1    = (const float*)d_in[5];
    const float* W2    = (const float*)d_in[6];
    float* out = (float*)d_out;

    char* ws = (char*)d_ws;
    _Float16*           g1      = (_Float16*)          (ws);              //  0 .. 25.6M
    _Float16*           g2      = (_Float16*)          (ws + 25600000);   // .. 38.4M
    _Float16*           agg2    = (_Float16*)          (ws + 38400000);   // .. 51.2M
    int*                rowptr  = (int*)               (ws + 51200000);   // +400,016
    unsigned long long* epack   = (unsigned long long*)(ws + 51600016);   // +6,400,000
    _Float16*           Wt1     = (_Float16*)          (ws + 58000016);   // +32,768
    _Float16*           Wt2     = (_Float16*)          (ws + 58032784);   // +16,384
    int*                hist    = (int*)               (ws + 58049168);   // +400,384
    int*                offpart = (int*)               (ws + 58449552);   // +400,384
    int*                bt      = (int*)               (ws + 58849936);   // +1,024
    int*                bbase   = (int*)               (ws + 58850960);   // +1,056
    unsigned long long* etmp    = (unsigned long long*)(ws + 58852016);   // +6,400,000 -> 65.3M

    // --- CSR build (no per-node global atomics anywhere) ---
    hist_both<<<N_TILES + 1, 256, 0, stream>>>(erows, hist, W1, W2, Wt1, Wt2);
    bucket_scan<<<N_BKT, 512, 0, stream>>>(hist, offpart, bt);
    bkt_base<<<1, 256, 0, stream>>>(bt, bbase);
    partition<<<N_TILES, 256, 0, stream>>>(erows, ecols, evals, offpart, bbase, etmp);
    bucket_reorder<<<N_BKT, 256, 0, stream>>>(bbase, etmp, epack, rowptr);

    // --- Layer 1 GEMM: g1 = x @ W1 (f16) ---
    gemm_mfma<128, true><<<(N_NODES + 63) / 64, 256, 0, stream>>>(x, Wt1, g1, N_NODES);

    // --- FUSED Layer1-aggregate + Layer2 GEMM: g2 = relu(A_sp@g1) @ W2 ---
    spmm_gemm_fused<<<(N_NODES + 63) / 64, 512, 0, stream>>>(
        rowptr, (const long long*)epack, g1, Wt2, g2, N_NODES);

    // --- Layer 2 aggregate: agg2 = A_sp @ g2 ---
    spmm_csr_h<64, false><<<(N_NODES + 31) / 32, 256, 0, stream>>>(
        rowptr, (const long long*)epack, g2, agg2, N_NODES);

    // --- Decode ---
    decode_dot<<<((N_PAIRS + 1) / 2 * 8 + 255) / 256, 256, 0, stream>>>(
        agg2, pairs, out, N_PAIRS);
}

// Round 14
// 140.613 us; speedup vs baseline: 1.3642x; 1.0384x over previous
//
#include <hip/hip_runtime.h>

#define N_NODES 100000
#define N_EDGES 800000
#define N_PAIRS 500000

#define T_TILE  2048
#define N_TILES ((N_EDGES + T_TILE - 1) / T_TILE)       // 391
#define N_BKT   256
#define NPB     391                                     // nodes per bucket (256*391 >= 100000)
#define BCAP    4096                                    // reorder staging capacity
#define GEMM_BLKS ((N_NODES + 63) / 64)                 // 1563

typedef _Float16 half4v __attribute__((ext_vector_type(4)));
typedef _Float16 half8v __attribute__((ext_vector_type(8)));
typedef float    f32x4  __attribute__((ext_vector_type(4)));

// ---------------------------------------------------------------------------
// XOR-16B LDS swizzle: byte ^= (row&7)<<4 -> fragment reads <=2-way (free).
// v_mfma_f32_16x16x16_f16: A: lane l holds A[l%16][4*(l/16)+i];
//   B: B[4*(l/16)+i][l%16]; D: D[4*(l/16)+i][l%16].
// ---------------------------------------------------------------------------
__device__ __forceinline__ int swz(int byte_off, int row) {
    return byte_off ^ ((row & 7) << 4);
}

// ---------------------------------------------------------------------------
// MERGED: blocks [0,256) = bucket_reorder; blocks [256,256+GEMM_BLKS) =
// g1 = x @ W1 MFMA gemm.  Independent work co-scheduled in one dispatch
// (same-stream kernels never overlap; reorder is latency-bound, gemm is
// MFMA-bound -> good CU co-residency).  Shared 48KB LDS pool, role-split.
// ---------------------------------------------------------------------------
__global__ __launch_bounds__(256) void reorder_and_gemm(
        const int* __restrict__ bbase,
        const unsigned long long* __restrict__ etmp,
        unsigned long long* __restrict__ epack,
        int* __restrict__ rowptr,
        const float* __restrict__ x,
        const _Float16* __restrict__ Wt1,
        _Float16* __restrict__ g1, int nRows) {
    __shared__ __align__(16) char smem[49152];
    const int t = threadIdx.x;

    if (blockIdx.x < N_BKT) {
        // ---- bucket_reorder: count local degrees, scan, write rowptr, rank.
        int*                lcnt = (int*)smem;                         // 392*4
        int*                psum = (int*)(smem + 1600);                // 256*4
        int*                lcur = (int*)(smem + 2624);                // 391*4
        unsigned long long* stg  = (unsigned long long*)(smem + 4224); // 4096*8

        const int b    = blockIdx.x;
        const int lo   = b * NPB;
        const int hiN  = min(lo + NPB, N_NODES);
        const int nloc = hiN - lo;
        const int base = bbase[b];
        const int cnt  = bbase[b + 1] - base;

        for (int j = t; j < NPB; j += 256) lcnt[j] = 0;
        __syncthreads();
        for (int i = t; i < cnt; i += 256)
            atomicAdd(&lcnt[(int)((etmp[base + i] >> 17) & 0x1FF)], 1);
        __syncthreads();
        const int j0 = 2 * t, j1 = 2 * t + 1;
        const int a0 = (j0 < NPB) ? lcnt[j0] : 0;
        const int a1 = (j1 < NPB) ? lcnt[j1] : 0;
        psum[t] = a0 + a1;
        __syncthreads();
        for (int o = 1; o < 256; o <<= 1) {
            int u = (t >= o) ? psum[t - o] : 0;
            __syncthreads();
            psum[t] += u;
            __syncthreads();
        }
        const int ex0 = psum[t] - (a0 + a1);
        const int ex1 = ex0 + a0;
        if (j0 < NPB) lcur[j0] = ex0;
        if (j1 < NPB) lcur[j1] = ex1;
        if (j0 < nloc) rowptr[lo + j0] = base + ex0;
        if (j1 < nloc) rowptr[lo + j1] = base + ex1;
        if (b == N_BKT - 1 && t == 0) rowptr[N_NODES] = N_EDGES;
        __syncthreads();
        for (int i = t; i < cnt; i += 256) {
            const unsigned long long p = etmp[base + i];
            const int lrow = (int)((p >> 17) & 0x1FF);
            const int pos  = atomicAdd(&lcur[lrow], 1);
            const unsigned long long rec = (p & 0xFFFFFFFF00000000ULL) | (p & 0x1FFFFULL);
            if (pos < BCAP) stg[pos] = rec;
            else epack[base + pos] = rec;   // safety fallback (statistically never)
        }
        __syncthreads();
        const int n = min(cnt, BCAP);
        for (int i = t; i < n; i += 256)
            epack[base + i] = stg[i];
        return;
    }

    // ---- gemm path: g1[64 rows, 128] = (f16)(x @ Wt1^T)
    constexpr int K = 128, M = 128, CT = M / 16;
    _Float16* Alds = (_Float16*)smem;               // 64*128*2  = 16384
    _Float16* Wlds = (_Float16*)(smem + 16384);     // 128*128*2 = 32768

    const int rb = (blockIdx.x - N_BKT) * 64;

    for (int idx = t; idx < 64 * (K / 4); idx += 256) {
        const int row = idx >> 5, c4 = idx & 31;
        const int rg = (rb + row < nRows) ? rb + row : nRows - 1;
        const float4 a = *(const float4*)&x[(long)rg * K + c4 * 4];
        half4v h = { (_Float16)a.x, (_Float16)a.y, (_Float16)a.z, (_Float16)a.w };
        *(half4v*)((char*)Alds + swz(row * 256 + c4 * 8, row)) = h;
    }
    for (int idx = t; idx < M * (K / 8); idx += 256) {
        const int col = idx >> 4, seg = idx & 15;
        const half8v h = *(const half8v*)&Wt1[col * K + seg * 8];
        *(half8v*)((char*)Wlds + swz(col * 256 + seg * 16, col)) = h;
    }
    __syncthreads();

    const int l  = t & 63;
    const int w  = t >> 6;
    const int lr = l & 15;
    const int lg = l >> 4;

    f32x4 acc[CT];
    #pragma unroll
    for (int ct = 0; ct < CT; ++ct) acc[ct] = (f32x4){0.f, 0.f, 0.f, 0.f};

    #pragma unroll
    for (int ks = 0; ks < K / 16; ++ks) {
        const int kb   = ks * 32 + lg * 8;
        const int arow = w * 16 + lr;
        const half4v af = *(const half4v*)((const char*)Alds + swz(arow * 256 + kb, arow));
        #pragma unroll
        for (int ct = 0; ct < CT; ++ct) {
            const int col = ct * 16 + lr;
            const half4v bf = *(const half4v*)((const char*)Wlds + swz(col * 256 + kb, col));
            acc[ct] = __builtin_amdgcn_mfma_f32_16x16x16f16(af, bf, acc[ct], 0, 0, 0);
        }
    }

    #pragma unroll
    for (int ct = 0; ct < CT; ++ct) {
        const int col = ct * 16 + lr;
        #pragma unroll
        for (int j = 0; j < 4; ++j) {
            const int row = rb + w * 16 + lg * 4 + j;
            if (row < nRows) g1[(long)row * M + col] = (_Float16)acc[ct][j];
        }
    }
}

// ---------------------------------------------------------------------------
// FUSED: g2[64 rows, 64] = relu(A_sp @ g1)[tile] @ Wt2^T.  512 thr / 8 waves.
// ---------------------------------------------------------------------------
__global__ __launch_bounds__(512) void spmm_gemm_fused(const int* __restrict__ rowptr,
                                                       const long long* __restrict__ epack,
                                                       const _Float16* __restrict__ g,
                                                       const _Float16* __restrict__ Wt2,
                                                       _Float16* __restrict__ g2, int nRows) {
    constexpr int K = 128, M = 64;
    __shared__ _Float16 Alds[64 * K];
    __shared__ _Float16 Wlds[M * K];

    const int rb = blockIdx.x * 64;

    for (int idx = threadIdx.x; idx < M * (K / 8); idx += 512) {
        const int col = idx >> 4, seg = idx & 15;
        const half8v h = *(const half8v*)&Wt2[col * K + seg * 8];
        *(half8v*)((char*)Wlds + swz(col * 256 + seg * 16, col)) = h;
    }

    const int li = threadIdx.x & 15;
    const int rs = threadIdx.x >> 4;        // 0..31
    #pragma unroll
    for (int s = 0; s < 2; ++s) {
        const int lrow = s * 32 + rs;
        const int r  = rb + lrow;
        const int rc = (r < nRows) ? r : nRows - 1;
        const int lo = rowptr[rc], hi = rowptr[rc + 1];
        float acc[8] = {0.f, 0.f, 0.f, 0.f, 0.f, 0.f, 0.f, 0.f};
        #pragma unroll 4
        for (int e = lo; e < hi; ++e) {
            const long long pk = epack[e];
            const int   c = (int)pk;
            const float v = __int_as_float((int)(pk >> 32));
            const half8v m = *(const half8v*)&g[(long)c * K + li * 8];
            #pragma unroll
            for (int j = 0; j < 8; ++j) acc[j] += v * (float)m[j];
        }
        half8v h;
        #pragma unroll
        for (int j = 0; j < 8; ++j) h[j] = (_Float16)fmaxf(acc[j], 0.f);
        *(half8v*)((char*)Alds + swz(lrow * 256 + li * 16, lrow)) = h;
    }
    __syncthreads();

    const int l    = threadIdx.x & 63;
    const int w    = threadIdx.x >> 6;      // 0..7
    const int lr   = l & 15;
    const int lg   = l >> 4;
    const int rowg = w >> 1;                // 0..3
    const int colb = (w & 1) * 32;          // 0 or 32

    f32x4 acc[2];
    acc[0] = (f32x4){0.f, 0.f, 0.f, 0.f};
    acc[1] = (f32x4){0.f, 0.f, 0.f, 0.f};

    #pragma unroll
    for (int ks = 0; ks < K / 16; ++ks) {
        const int kb   = ks * 32 + lg * 8;
        const int arow = rowg * 16 + lr;
        const half4v af = *(const half4v*)((const char*)Alds + swz(arow * 256 + kb, arow));
        #pragma unroll
        for (int ct = 0; ct < 2; ++ct) {
            const int col = colb + ct * 16 + lr;
            const half4v bf = *(const half4v*)((const char*)Wlds + swz(col * 256 + kb, col));
            acc[ct] = __builtin_amdgcn_mfma_f32_16x16x16f16(af, bf, acc[ct], 0, 0, 0);
        }
    }

    #pragma unroll
    for (int ct = 0; ct < 2; ++ct) {
        const int col = colb + ct * 16 + lr;
        #pragma unroll
        for (int j = 0; j < 4; ++j) {
            const int row = rb + rowg * 16 + lg * 4 + j;
            if (row < nRows) g2[(long)row * M + col] = (_Float16)acc[ct][j];
        }
    }
}

// ---------------------------------------------------------------------------
// hist_both: per-(tile,bucket) LDS histogram (no per-node global atomics).
// Block N_TILES: W transpose + zero the bucket_scan done-counter.
// ---------------------------------------------------------------------------
__global__ __launch_bounds__(256) void hist_both(const int* __restrict__ erows,
                                                 int* __restrict__ hist,
                                                 const float* __restrict__ W1,
                                                 const float* __restrict__ W2,
                                                 _Float16* __restrict__ Wt1,
                                                 _Float16* __restrict__ Wt2,
                                                 int* __restrict__ done) {
    if (blockIdx.x == N_TILES) {
        if (threadIdx.x == 0) *done = 0;
        for (int i = threadIdx.x; i < 128 * 128; i += 256) {
            const int k = i >> 7, m = i & 127;
            Wt1[m * 128 + k] = (_Float16)W1[i];
        }
        for (int i = threadIdx.x; i < 128 * 64; i += 256) {
            const int k = i >> 6, m = i & 63;
            Wt2[m * 128 + k] = (_Float16)W2[i];
        }
        return;
    }
    __shared__ int cnt[N_BKT];
    cnt[threadIdx.x] = 0;
    __syncthreads();
    const int e0 = blockIdx.x * T_TILE;
    const int e1 = min(e0 + T_TILE, N_EDGES);
    for (int e = e0 + threadIdx.x; e < e1; e += 256)
        atomicAdd(&cnt[erows[e] / NPB], 1);
    __syncthreads();
    hist[blockIdx.x * N_BKT + threadIdx.x] = cnt[threadIdx.x];
}

// ---------------------------------------------------------------------------
// bucket_scan: per-bucket prefix over tile counts -> offpart[b][t] + bt[b];
// LAST block (done-counter) also scans the 256 bucket totals -> bbase.
// ---------------------------------------------------------------------------
__global__ __launch_bounds__(512) void bucket_scan(const int* __restrict__ hist,
                                                   int* __restrict__ offpart,
                                                   int* __restrict__ bt,
                                                   int* __restrict__ bbase,
                                                   int* __restrict__ done) {
    __shared__ int lds[512];
    const int b = blockIdx.x;
    const int t = threadIdx.x;
    const int v = (t < N_TILES) ? hist[t * N_BKT + b] : 0;
    lds[t] = v;
    __syncthreads();
    for (int o = 1; o < 512; o <<= 1) {
        int u = (t >= o) ? lds[t - o] : 0;
        __syncthreads();
        lds[t] += u;
        __syncthreads();
    }
    if (t < N_TILES) offpart[b * N_TILES + t] = lds[t] - v;
    if (t == 511) bt[b] = lds[511];

    __shared__ int lastf;
    __syncthreads();
    if (t == 0) {
        __threadfence();
        lastf = (atomicAdd(done, 1) == gridDim.x - 1) ? 1 : 0;
    }
    __syncthreads();
    if (lastf) {
        __threadfence();
        __shared__ int lds2[256];
        int bv = 0;
        if (t < 256) { bv = bt[t]; lds2[t] = bv; }
        __syncthreads();
        for (int o = 1; o < 256; o <<= 1) {
            int u = (t < 256 && t >= o) ? lds2[t - o] : 0;
            __syncthreads();
            if (t < 256) lds2[t] += u;
            __syncthreads();
        }
        if (t < 256) bbase[t] = lds2[t] - bv;
        if (t == 255) bbase[256] = lds2[255];
    }
}

// ---------------------------------------------------------------------------
// partition: coarse scatter into per-bucket regions (tmp order).
// tmp record: [val:32][lrow:9][col:17].
// ---------------------------------------------------------------------------
__global__ __launch_bounds__(256) void partition(const int* __restrict__ erows,
                                                 const int* __restrict__ ecols,
                                                 const float* __restrict__ evals,
                                                 const int* __restrict__ offpart,
                                                 const int* __restrict__ bbase,
                                                 unsigned long long* __restrict__ etmp) {
    __shared__ int cur[N_BKT];
    cur[threadIdx.x] = bbase[threadIdx.x] + offpart[threadIdx.x * N_TILES + blockIdx.x];
    __syncthreads();
    const int e0 = blockIdx.x * T_TILE;
    const int e1 = min(e0 + T_TILE, N_EDGES);
    for (int e = e0 + threadIdx.x; e < e1; e += 256) {
        const int r = erows[e];
        const int b = r / NPB;
        const int lrow = r - b * NPB;
        const int p = atomicAdd(&cur[b], 1);
        etmp[p] = ((unsigned long long)(unsigned)__float_as_int(evals[e]) << 32)
                | ((unsigned)lrow << 17) | (unsigned)ecols[e];
    }
}

// ---------------------------------------------------------------------------
// CSR SpMM (gather, fp16 data, f32 accumulate): agg[r] = sum vals*g[cols]
// ---------------------------------------------------------------------------
template<int D, bool RELU>
__global__ __launch_bounds__(256) void spmm_csr_h(const int* __restrict__ rowptr,
                                                  const long long* __restrict__ epack,
                                                  const _Float16* __restrict__ g,
                                                  _Float16* __restrict__ agg, int nRows) {
    constexpr int LPR = D / 8;
    constexpr int RPB = 256 / LPR;
    const int r  = blockIdx.x * RPB + threadIdx.x / LPR;
    const int li = threadIdx.x % LPR;
    if (r >= nRows) return;
    const int lo = rowptr[r], hi = rowptr[r + 1];
    float acc[8] = {0.f, 0.f, 0.f, 0.f, 0.f, 0.f, 0.f, 0.f};
    #pragma unroll 4
    for (int e = lo; e < hi; ++e) {
        const long long pk = epack[e];
        const int   c = (int)pk;
        const float v = __int_as_float((int)(pk >> 32));
        const half8v m = *(const half8v*)&g[(long)c * D + li * 8];
        #pragma unroll
        for (int j = 0; j < 8; ++j) acc[j] += v * (float)m[j];
    }
    half8v o;
    #pragma unroll
    for (int j = 0; j < 8; ++j) {
        float a = RELU ? fmaxf(acc[j], 0.f) : acc[j];
        o[j] = (_Float16)a;
    }
    *(half8v*)&agg[(long)r * D + li * 8] = o;
}

// ---------------------------------------------------------------------------
// Decode: 2 pairs per thread (independent gather chains), 8 lanes per pair.
// ---------------------------------------------------------------------------
__global__ __launch_bounds__(256) void decode_dot(const _Float16* __restrict__ h2,
                                                  const int2* __restrict__ pairs,
                                                  float* __restrict__ out, int nPairs) {
    const int tid  = blockIdx.x * 256 + threadIdx.x;
    const int half = (nPairs + 1) / 2;
    const int p0   = tid >> 3;
    const int lane = tid & 7;
    if (p0 >= half) return;
    const int p1 = p0 + half;
    const bool has1 = p1 < nPairs;
    const int2 pr0 = pairs[p0];
    const int2 pr1 = has1 ? pairs[p1] : pr0;
    const half8v a0 = *(const half8v*)&h2[(long)pr0.x * 64 + lane * 8];
    const half8v b0 = *(const half8v*)&h2[(long)pr0.y * 64 + lane * 8];
    const half8v a1 = *(const half8v*)&h2[(long)pr1.x * 64 + lane * 8];
    const half8v b1 = *(const half8v*)&h2[(long)pr1.y * 64 + lane * 8];
    float s0 = 0.f, s1 = 0.f;
    #pragma unroll
    for (int j = 0; j < 8; ++j) {
        s0 += (float)a0[j] * (float)b0[j];
        s1 += (float)a1[j] * (float)b1[j];
    }
    s0 += __shfl_xor(s0, 1); s1 += __shfl_xor(s1, 1);
    s0 += __shfl_xor(s0, 2); s1 += __shfl_xor(s1, 2);
    s0 += __shfl_xor(s0, 4); s1 += __shfl_xor(s1, 4);
    if (lane == 0) {
        out[p0] = s0;
        if (has1) out[p1] = s1;
    }
}

// ---------------------------------------------------------------------------
extern "C" void kernel_launch(void* const* d_in, const int* in_sizes, int n_in,
                              void* d_out, int out_size, void* d_ws, size_t ws_size,
                              hipStream_t stream) {
    const float* x     = (const float*)d_in[0];
    const int*   erows = (const int*)d_in[1];
    const int*   ecols = (const int*)d_in[2];
    const float* evals = (const float*)d_in[3];
    const int2*  pairs = (const int2*)d_in[4];
    const float* W1    = (const float*)d_in[5];
    const float* W2    = (const float*)d_in[6];
    float* out = (float*)d_out;

    char* ws = (char*)d_ws;
    _Float16*           g1      = (_Float16*)          (ws);              //  0 .. 25.6M
    _Float16*           g2      = (_Float16*)          (ws + 25600000);   // .. 38.4M
    _Float16*           agg2    = (_Float16*)          (ws + 38400000);   // .. 51.2M
    int*                rowptr  = (int*)               (ws + 51200000);   // +400,016
    unsigned long long* epack   = (unsigned long long*)(ws + 51600016);   // +6,400,000
    _Float16*           Wt1     = (_Float16*)          (ws + 58000016);   // +32,768
    _Float16*           Wt2     = (_Float16*)          (ws + 58032784);   // +16,384
    int*                hist    = (int*)               (ws + 58049168);   // +400,384
    int*                offpart = (int*)               (ws + 58449552);   // +400,384
    int*                bt      = (int*)               (ws + 58849936);   // +1,024
    int*                bbase   = (int*)               (ws + 58850960);   // +1,056
    int*                done    = (int*)               (ws + 58852016);   // +16
    unsigned long long* etmp    = (unsigned long long*)(ws + 58852032);   // +6,400,000 -> 65.3M

    // --- CSR build (no per-node global atomics anywhere) ---
    hist_both<<<N_TILES + 1, 256, 0, stream>>>(erows, hist, W1, W2, Wt1, Wt2, done);
    bucket_scan<<<N_BKT, 512, 0, stream>>>(hist, offpart, bt, bbase, done);
    partition<<<N_TILES, 256, 0, stream>>>(erows, ecols, evals, offpart, bbase, etmp);

    // --- bucket_reorder (blocks 0..255) co-launched with gemm1 (rest) ---
    reorder_and_gemm<<<N_BKT + GEMM_BLKS, 256, 0, stream>>>(
        bbase, etmp, epack, rowptr, x, Wt1, g1, N_NODES);

    // --- FUSED Layer1-aggregate + Layer2 GEMM: g2 = relu(A_sp@g1) @ W2 ---
    spmm_gemm_fused<<<GEMM_BLKS, 512, 0, stream>>>(
        rowptr, (const long long*)epack, g1, Wt2, g2, N_NODES);

    // --- Layer 2 aggregate: agg2 = A_sp @ g2 ---
    spmm_csr_h<64, false><<<(N_NODES + 31) / 32, 256, 0, stream>>>(
        rowptr, (const long long*)epack, g2, agg2, N_NODES);

    // --- Decode ---
    decode_dot<<<((N_PAIRS + 1) / 2 * 8 + 255) / 256, 256, 0, stream>>>(
        agg2, pairs, out, N_PAIRS);
}